// Round 11
// baseline (904.373 us; speedup 1.0000x reference)
//
#include <hip/hip_runtime.h>
#include <hip/hip_bf16.h>

typedef __hip_bfloat16 bf16;
typedef __bf16 v8bf __attribute__((ext_vector_type(8)));
typedef float f32x4 __attribute__((ext_vector_type(4)));
typedef unsigned int v4u __attribute__((ext_vector_type(4)));

constexpr int N = 20000, M = 1024, E = 640000, D = 256;
constexpr size_t SEGEL = (size_t)N * D;
constexpr int NCHUNK = 10000;
constexpr int NSLICE = 64;
constexpr int ESLICE = E / NSLICE;  // 10000

__device__ __forceinline__ float b2f(bf16 v) { return __bfloat162float(v); }
__device__ __forceinline__ bf16 f2b(float f) { return __float2bfloat16(f); }
__device__ __forceinline__ float u2f(unsigned short u) { return __uint_as_float(((unsigned)u) << 16); }
__device__ __forceinline__ unsigned short f2u(float f) { bf16 h = __float2bfloat16(f); return *(unsigned short*)&h; }
__device__ __forceinline__ float loadf(const void* p, size_t i, int isbf) {
    return isbf ? b2f(((const bf16*)p)[i]) : ((const float*)p)[i];
}
__device__ __forceinline__ void fma8(float* acc, uint4 v, float w) {
    acc[0] = fmaf(w, u2f((unsigned short)(v.x & 0xffffu)), acc[0]);
    acc[1] = fmaf(w, u2f((unsigned short)(v.x >> 16)), acc[1]);
    acc[2] = fmaf(w, u2f((unsigned short)(v.y & 0xffffu)), acc[2]);
    acc[3] = fmaf(w, u2f((unsigned short)(v.y >> 16)), acc[3]);
    acc[4] = fmaf(w, u2f((unsigned short)(v.z & 0xffffu)), acc[4]);
    acc[5] = fmaf(w, u2f((unsigned short)(v.z >> 16)), acc[5]);
    acc[6] = fmaf(w, u2f((unsigned short)(v.w & 0xffffu)), acc[6]);
    acc[7] = fmaf(w, u2f((unsigned short)(v.w >> 16)), acc[7]);
}
__device__ __forceinline__ void add4(float* acc, uint2 v) {
    acc[0] += u2f((unsigned short)(v.x & 0xffffu));
    acc[1] += u2f((unsigned short)(v.x >> 16));
    acc[2] += u2f((unsigned short)(v.y & 0xffffu));
    acc[3] += u2f((unsigned short)(v.y >> 16));
}
__device__ __forceinline__ unsigned pack2(float a, float b) {
    return (unsigned)f2u(a) | ((unsigned)f2u(b) << 16);
}

// ---------------------------------------------------------------------------
__global__ void detect_kernel(const void* __restrict__ ea, int* __restrict__ flag)
{
    if (threadIdx.x == 0 && blockIdx.x == 0) {
        const unsigned short* u = (const unsigned short*)ea;
        int cnt = 0;
        for (int i = 0; i < 64; i++) {
            float f = __uint_as_float(((unsigned)u[i]) << 16);
            if (f >= 0.05f && f <= 1.05f) cnt++;
        }
        *flag = (cnt >= 60) ? 1 : 0;
    }
}

// ---------------------------------------------------------------------------
// Merged weight-transpose (blocks 0..2303) + col-emb MLP table (2304..3327).
__global__ __launch_bounds__(256) void prep_kernel(
    const void* __restrict__ W0, const void* __restrict__ W1, const void* __restrict__ W2,
    const void* __restrict__ pW1, const void* __restrict__ pb1,
    const void* __restrict__ pW2, const void* __restrict__ pb2,
    bf16* __restrict__ WT, bf16* __restrict__ cemb, const int* __restrict__ flag)
{
    int isbf = *flag;
    int b = blockIdx.x;
    if (b < 2304) {
        int mat = b >> 8, n = b & 255, k = threadIdx.x;
        const void* W = (mat < 3) ? W0 : (mat < 6) ? W1 : W2;
        int lm = mat - (mat < 3 ? 0 : (mat < 6 ? 3 : 6));
        WT[(size_t)mat * 65536 + n * 256 + k] =
            f2b(loadf(W, (size_t)lm * 65536 + k * 256 + n, isbf));
    } else {
        int j = b - 2304;           // 0..1023
        int d = threadIdx.x;
        float jf = (float)j;
        float acc = loadf(pb2, d, isbf);
        #pragma unroll
        for (int k = 0; k < 16; k++) {
            float h = fmaxf(jf * loadf(pW1, k, isbf) + loadf(pb1, k, isbf), 0.0f);
            acc += h * loadf(pW2, k * 256 + d, isbf);
        }
        cemb[(size_t)j * 256 + d] = f2b(acc);
    }
}

// ---------------------------------------------------------------------------
// x0[i] = mean_{j: init[i][j]!=0} cemb[j]  — wave per node, sparse gather,
// 8-deep unroll for outstanding L2 reads.
__global__ __launch_bounds__(256) void projection_kernel(
    const void* __restrict__ init, const bf16* __restrict__ cemb,
    bf16* __restrict__ x0, const int* __restrict__ flag)
{
    __shared__ unsigned short idxs[4][1024];
    int isbf = *flag;
    int wave = threadIdx.x >> 6, lane = threadIdx.x & 63;
    int i = blockIdx.x * 4 + wave;
    unsigned long long below = (lane == 63) ? 0x7fffffffffffffffull
                                            : ((1ull << lane) - 1ull);
    int cnt = 0;
    if (isbf) {
        const unsigned short* row = (const unsigned short*)init + (size_t)i * 1024;
        for (int c0 = 0; c0 < 1024; c0 += 64) {
            bool nz = (row[c0 + lane] & 0x7fffu) != 0;
            unsigned long long m = __ballot(nz);
            if (nz) idxs[wave][cnt + __popcll(m & below)] = (unsigned short)(c0 + lane);
            cnt += __popcll(m);
        }
    } else {
        const float* row = (const float*)init + (size_t)i * 1024;
        for (int c0 = 0; c0 < 1024; c0 += 64) {
            bool nz = row[c0 + lane] != 0.0f;
            unsigned long long m = __ballot(nz);
            if (nz) idxs[wave][cnt + __popcll(m & below)] = (unsigned short)(c0 + lane);
            cnt += __popcll(m);
        }
    }
    const uint2* cr = (const uint2*)cemb;     // 64 uint2 per 256-elem row
    float acc[4] = {0.0f, 0.0f, 0.0f, 0.0f};
    int j = 0;
    for (; j + 8 <= cnt; j += 8) {
        uint2 v0 = cr[(size_t)idxs[wave][j + 0] * 64 + lane];
        uint2 v1 = cr[(size_t)idxs[wave][j + 1] * 64 + lane];
        uint2 v2 = cr[(size_t)idxs[wave][j + 2] * 64 + lane];
        uint2 v3 = cr[(size_t)idxs[wave][j + 3] * 64 + lane];
        uint2 v4 = cr[(size_t)idxs[wave][j + 4] * 64 + lane];
        uint2 v5 = cr[(size_t)idxs[wave][j + 5] * 64 + lane];
        uint2 v6 = cr[(size_t)idxs[wave][j + 6] * 64 + lane];
        uint2 v7 = cr[(size_t)idxs[wave][j + 7] * 64 + lane];
        add4(acc, v0); add4(acc, v1); add4(acc, v2); add4(acc, v3);
        add4(acc, v4); add4(acc, v5); add4(acc, v6); add4(acc, v7);
    }
    for (; j < cnt; j++) {
        uint2 v = cr[(size_t)idxs[wave][j] * 64 + lane];
        add4(acc, v);
    }
    float rinv = 1.0f / fmaxf((float)cnt, 1.0f);
    uint2 o;
    o.x = pack2(acc[0] * rinv, acc[1] * rinv);
    o.y = pack2(acc[2] * rinv, acc[3] * rinv);
    ((uint2*)x0)[(size_t)i * 64 + lane] = o;
}

// ---------------------------------------------------------------------------
// Atomic-free CSR build (LDS histogram counting sort), edges packed as int2.
__global__ __launch_bounds__(256) void countP_kernel(
    const int* __restrict__ e0, const int* __restrict__ e1, const int* __restrict__ e2,
    int* __restrict__ P)
{
    __shared__ int cur[NCHUNK];
    int b = blockIdx.x;
    int pb = b >> 7, rem = b & 127;
    int ck = rem >> 6, s = rem & 63;
    const int* ei = pb == 0 ? e0 : pb == 1 ? e1 : e2;
    int c0 = ck * NCHUNK;
    int t = threadIdx.x;
    for (int i = t; i < NCHUNK; i += 256) cur[i] = 0;
    __syncthreads();
    int ebase = s * ESLICE;
    for (int e = ebase + t; e < ebase + ESLICE; e += 256) {
        int c = ei[E + e];
        if (c >= c0 && c < c0 + NCHUNK) atomicAdd(&cur[c - c0], 1);
    }
    __syncthreads();
    int* Prow = P + ((size_t)(pb * NSLICE + s)) * N + c0;
    for (int i = t; i < NCHUNK; i += 256) Prow[i] = cur[i];
}

__global__ __launch_bounds__(256) void cnt_sum_kernel(
    const int* __restrict__ P, int* __restrict__ cnt)
{
    int id = blockIdx.x * 256 + threadIdx.x;
    if (id >= 3 * N) return;
    int pb = id / N, c = id - pb * N;
    int sum = 0;
    #pragma unroll 8
    for (int s = 0; s < NSLICE; s++)
        sum += P[((size_t)(pb * NSLICE + s)) * N + c];
    cnt[id] = sum;
}

__global__ __launch_bounds__(1024) void scan_kernel(
    const int* __restrict__ cnt, int* __restrict__ col_ptr)
{
    int pb = blockIdx.x;
    int base = pb * E;
    __shared__ int s[1024];
    int t = threadIdx.x;
    const int CH = 20;
    int i0 = t * CH;
    int sum = 0;
    for (int j = 0; j < CH; j++) { int i = i0 + j; if (i < N) sum += cnt[pb * N + i]; }
    s[t] = sum;
    __syncthreads();
    for (int off = 1; off < 1024; off <<= 1) {
        int v = (t >= off) ? s[t - off] : 0;
        __syncthreads();
        s[t] += v;
        __syncthreads();
    }
    int run = base + s[t] - sum;
    for (int j = 0; j < CH; j++) {
        int i = i0 + j;
        if (i < N) {
            col_ptr[pb * (N + 1) + i] = run;
            run += cnt[pb * N + i];
        }
    }
    if (t == 0) col_ptr[pb * (N + 1) + N] = base + E;
}

__global__ __launch_bounds__(256) void base_kernel(
    int* __restrict__ P, const int* __restrict__ col_ptr)
{
    int id = blockIdx.x * 256 + threadIdx.x;
    if (id >= 3 * N) return;
    int pb = id / N, c = id - pb * N;
    int run = col_ptr[pb * (N + 1) + c];
    for (int s = 0; s < NSLICE; s++) {
        size_t idx = ((size_t)(pb * NSLICE + s)) * N + c;
        int v = P[idx];
        P[idx] = run;
        run += v;
    }
}

// epack[pos] = (row, raw weight bits)
__global__ __launch_bounds__(256) void fill_kernel(
    const int* __restrict__ e0, const int* __restrict__ e1, const int* __restrict__ e2,
    const void* __restrict__ a0, const void* __restrict__ a1, const void* __restrict__ a2,
    const int* __restrict__ P, int2* __restrict__ epack, const int* __restrict__ flag)
{
    __shared__ int cur[NCHUNK];
    int isbf = *flag;
    int b = blockIdx.x;
    int pb = b >> 7, rem = b & 127;
    int ck = rem >> 6, s = rem & 63;
    const int* ei = pb == 0 ? e0 : pb == 1 ? e1 : e2;
    const void* ea = pb == 0 ? a0 : pb == 1 ? a1 : a2;
    int c0 = ck * NCHUNK;
    int t = threadIdx.x;
    const int* Prow = P + ((size_t)(pb * NSLICE + s)) * N + c0;
    for (int i = t; i < NCHUNK; i += 256) cur[i] = Prow[i];
    __syncthreads();
    int ebase = s * ESLICE;
    for (int e = ebase + t; e < ebase + ESLICE; e += 256) {
        int c = ei[E + e];
        if (c >= c0 && c < c0 + NCHUNK) {
            int r = ei[e];
            float w = loadf(ea, e, isbf);
            int pos = atomicAdd(&cur[c - c0], 1);
            int2 v; v.x = r; v.y = __float_as_int(w);
            epack[pos] = v;
        }
    }
}

// deg = 1 + sum(w_raw) -> dinv, nloop  (wave per node)
__global__ __launch_bounds__(256) void degsum_kernel(
    const int* __restrict__ col_ptr, const int2* __restrict__ epack,
    float* __restrict__ dinv, float* __restrict__ nloop)
{
    int wave = threadIdx.x >> 6, lane = threadIdx.x & 63;
    int pb = blockIdx.x / 5000;
    int i = (blockIdx.x - pb * 5000) * 4 + wave;
    int start = col_ptr[pb * (N + 1) + i], end = col_ptr[pb * (N + 1) + i + 1];
    float sum = 0.0f;
    for (int p = start + lane; p < end; p += 64) sum += __int_as_float(epack[p].y);
    for (int off = 1; off < 64; off <<= 1) sum += __shfl_xor(sum, off, 64);
    if (lane == 0) {
        float dg = 1.0f + sum;
        dinv[pb * N + i] = rsqrtf(dg);
        nloop[pb * N + i] = 1.0f / dg;
    }
}

// epack[p].y = dinv[c]*w_raw*dinv[r], then per-64-chunk bitonic sort by src
// (sorted lists -> concurrent waves share a moving L2 window).
__global__ __launch_bounds__(256) void snorm_sort_kernel(
    const int* __restrict__ col_ptr, int2* __restrict__ epack,
    const float* __restrict__ dinv)
{
    int wave = threadIdx.x >> 6, lane = threadIdx.x & 63;
    int pb = blockIdx.x / 5000;
    int i = (blockIdx.x - pb * 5000) * 4 + wave;
    int start = col_ptr[pb * (N + 1) + i], end = col_ptr[pb * (N + 1) + i + 1];
    float dc = dinv[pb * N + i];
    for (int base = start; base < end; base += 64) {
        int n = end - base; n = n < 64 ? n : 64;
        int key = 0x7fffffff, val = 0;
        if (lane < n) {
            int2 v = epack[base + lane];
            key = v.x;
            val = __float_as_int(dc * __int_as_float(v.y) * dinv[pb * N + v.x]);
        }
        #pragma unroll
        for (int k = 2; k <= 64; k <<= 1) {
            #pragma unroll
            for (int j = k >> 1; j > 0; j >>= 1) {
                int pk = __shfl_xor(key, j, 64);
                int pv = __shfl_xor(val, j, 64);
                bool up = (lane & k) == 0;
                bool lower = (lane & j) == 0;
                bool takeMin = (up == lower);
                bool sw = takeMin ? (pk < key) : (pk > key);
                if (sw) { key = pk; val = pv; }
            }
        }
        if (lane < n) {
            int2 o; o.x = key; o.y = val;
            epack[base + lane] = o;
        }
    }
}

// ---------------------------------------------------------------------------
// Wave-per-node aggregation; half-wave per edge, 16B gathers; NT streaming
// for epack (read-once) and ybuf (write-once) so they don't evict x from L2.
__global__ __launch_bounds__(256) void aggregate_kernel(
    const bf16* __restrict__ xi0, const bf16* __restrict__ xi1, const bf16* __restrict__ xi2,
    bf16* __restrict__ yb,
    const int* __restrict__ col_ptr, const int2* __restrict__ epack,
    const float* __restrict__ nloop)
{
    int wave = threadIdx.x >> 6, lane = threadIdx.x & 63;
    int pb = blockIdx.x / 5000;
    int i = (blockIdx.x - pb * 5000) * 4 + wave;
    const bf16* x = pb == 0 ? xi0 : pb == 1 ? xi1 : xi2;
    const uint4* xr = (const uint4*)x;           // 32 uint4 per row
    int L = lane & 31, h = lane >> 5;
    int start = col_ptr[pb * (N + 1) + i], end = col_ptr[pb * (N + 1) + i + 1];
    float nl = nloop[pb * N + i];
    float acc[8];
    {
        uint4 sv = xr[(size_t)i * 32 + L];
        float self = (h == 0) ? nl : 0.0f;
        #pragma unroll
        for (int j = 0; j < 8; j++) acc[j] = 0.0f;
        fma8(acc, sv, self);
    }
    for (int base = start; base < end; base += 64) {
        int n = end - base; n = n < 64 ? n : 64;
        int ex = 0, ey = 0;
        if (lane < n) {
            unsigned long long ev = __builtin_nontemporal_load(
                (const unsigned long long*)(epack + base + lane));
            ex = (int)(unsigned)(ev & 0xffffffffull);
            ey = (int)(unsigned)(ev >> 32);
        }
        #pragma unroll 8
        for (int jj = 0; jj < n; jj += 2) {
            int rj = __shfl(ex, jj + h, 64);      // jj+h==n hits w=0 lane: safe
            float wj = __int_as_float(__shfl(ey, jj + h, 64));
            uint4 v = xr[(size_t)rj * 32 + L];
            fma8(acc, v, wj);
        }
    }
    #pragma unroll
    for (int j = 0; j < 8; j++) acc[j] += __shfl_xor(acc[j], 32, 64);
    if (h == 0) {
        v4u o;
        o.x = pack2(acc[0], acc[1]);
        o.y = pack2(acc[2], acc[3]);
        o.z = pack2(acc[4], acc[5]);
        o.w = pack2(acc[6], acc[7]);
        __builtin_nontemporal_store(o,
            (v4u*)yb + (size_t)pb * (SEGEL / 8) + (size_t)i * 32 + L);
    }
}

// ---------------------------------------------------------------------------
// xout = relu(y @ W + b). One block per 32 rows x full 256 cols (y read once).
__global__ __launch_bounds__(256) void gemm_relu_kernel(
    const bf16* __restrict__ yb, const bf16* __restrict__ WT, int layer,
    const void* __restrict__ b0, const void* __restrict__ b1, const void* __restrict__ b2,
    bf16* __restrict__ o0, bf16* __restrict__ o1, bf16* __restrict__ o2,
    const int* __restrict__ flag)
{
    int isbf = *flag;
    int pl = blockIdx.x / 625, blk = blockIdx.x - pl * 625;
    const bf16* y = yb + (size_t)pl * SEGEL;
    const bf16* wt = WT + (size_t)(pl * 3 + layer) * 65536;
    const void* bias = pl == 0 ? b0 : pl == 1 ? b1 : b2;
    bf16* xout = pl == 0 ? o0 : pl == 1 ? o1 : o2;

    int wave = threadIdx.x >> 6, lane = threadIdx.x & 63;
    int m0 = blk * 32 + (wave >> 1) * 16;
    int n0 = (wave & 1) * 128;
    int mrow = lane & 15, q = lane >> 4;

    f32x4 acc[8] = {};
    const v8bf* arow = reinterpret_cast<const v8bf*>(y + (size_t)(m0 + mrow) * 256);
    for (int k0 = 0; k0 < 256; k0 += 32) {
        v8bf a = arow[(k0 >> 3) + q];
        #pragma unroll
        for (int nt = 0; nt < 8; nt++) {
            const v8bf* brow = reinterpret_cast<const v8bf*>(wt + (size_t)(n0 + nt * 16 + mrow) * 256);
            acc[nt] = __builtin_amdgcn_mfma_f32_16x16x32_bf16(a, brow[(k0 >> 3) + q], acc[nt], 0, 0, 0);
        }
    }
    #pragma unroll
    for (int nt = 0; nt < 8; nt++) {
        int col = n0 + nt * 16 + mrow;
        float bv = loadf(bias, (size_t)layer * 256 + col, isbf);
        #pragma unroll
        for (int r = 0; r < 4; r++) {
            int row = m0 + q * 4 + r;
            xout[(size_t)row * 256 + col] = f2b(fmaxf(acc[nt][r] + bv, 0.0f));
        }
    }
}

// ---------------------------------------------------------------------------
__global__ __launch_bounds__(256) void attention_kernel(
    const bf16* __restrict__ e0, const bf16* __restrict__ e1, const bf16* __restrict__ e2,
    const void* __restrict__ w_att, void* __restrict__ out, int n_nodes,
    const int* __restrict__ flag)
{
    int isbf = *flag;
    int wave = threadIdx.x >> 6, lane = threadIdx.x & 63;
    int n = blockIdx.x * 4 + wave;
    if (n >= n_nodes) return;
    int d0 = lane * 4;
    float w[4], v0[4], v1[4], v2[4];
    #pragma unroll
    for (int j = 0; j < 4; j++) {
        w[j]  = loadf(w_att, d0 + j, isbf);
        v0[j] = b2f(e0[(size_t)n * 256 + d0 + j]);
        v1[j] = b2f(e1[(size_t)n * 256 + d0 + j]);
        v2[j] = b2f(e2[(size_t)n * 256 + d0 + j]);
    }
    float s0 = 0, s1 = 0, s2 = 0;
    #pragma unroll
    for (int j = 0; j < 4; j++) { s0 += v0[j] * w[j]; s1 += v1[j] * w[j]; s2 += v2[j] * w[j]; }
    for (int off = 1; off < 64; off <<= 1) {
        s0 += __shfl_xor(s0, off, 64);
        s1 += __shfl_xor(s1, off, 64);
        s2 += __shfl_xor(s2, off, 64);
    }
    float m = fmaxf(s0, fmaxf(s1, s2));
    float a0 = expf(s0 - m), a1 = expf(s1 - m), a2 = expf(s2 - m);
    float inv = 1.0f / (a0 + a1 + a2);
    a0 *= inv; a1 *= inv; a2 *= inv;
    #pragma unroll
    for (int j = 0; j < 4; j++) {
        float v = a0 * v0[j] + a1 * v1[j] + a2 * v2[j];
        if (isbf) ((bf16*)out)[(size_t)n * 256 + d0 + j] = f2b(v);
        else      ((float*)out)[(size_t)n * 256 + d0 + j] = v;
    }
}

// ---------------------------------------------------------------------------
extern "C" void kernel_launch(void* const* d_in, const int* in_sizes, int n_in,
                              void* d_out, int out_size, void* d_ws, size_t ws_size,
                              hipStream_t stream)
{
    (void)in_sizes; (void)n_in; (void)out_size; (void)ws_size;

    const void* init = d_in[0];
    const int*  ei[3] = {(const int*)d_in[1], (const int*)d_in[2], (const int*)d_in[3]};
    const void* ea[3] = {d_in[4], d_in[5], d_in[6]};
    const void* pW1 = d_in[7];
    const void* pb1 = d_in[8];
    const void* pW2 = d_in[9];
    const void* pb2 = d_in[10];
    const void* Wb[3] = {d_in[11], d_in[13], d_in[15]};
    const void* bb[3] = {d_in[12], d_in[14], d_in[16]};
    const void* w_att = d_in[17];

    char* ws = (char*)d_ws;
    size_t off = 0;
    auto carve = [&](size_t bytes) -> char* {
        off = (off + 255) & ~(size_t)255;
        char* p = ws + off; off += bytes; return p;
    };
    int*   flag  = (int*)carve(4);
    bf16*  WT    = (bf16*)carve((size_t)9 * 65536 * 2);
    bf16*  cemb  = (bf16*)carve((size_t)M * D * 2);
    bf16*  x0    = (bf16*)carve(SEGEL * 2);
    int*   cnt   = (int*)carve((size_t)3 * N * 4);
    int*   colp  = (int*)carve((size_t)3 * (N + 1) * 4);
    float* dinv  = (float*)carve((size_t)3 * N * 4);
    float* nloop = (float*)carve((size_t)3 * N * 4);
    int2*  epack = (int2*)carve((size_t)3 * E * 8);
    bf16*  ybuf  = (bf16*)carve((size_t)3 * SEGEL * 2);
    bf16*  bufA  = (bf16*)carve((size_t)3 * SEGEL * 2);
    bf16*  bufB  = (bf16*)carve((size_t)3 * SEGEL * 2);
    // P (15.36 MB) aliases bufB: dead before bufB's first write (layer-1 out)
    int* P = (int*)bufB;

    detect_kernel<<<1, 64, 0, stream>>>(ea[0], flag);
    prep_kernel<<<3328, 256, 0, stream>>>(Wb[0], Wb[1], Wb[2],
                                          pW1, pb1, pW2, pb2, WT, cemb, flag);
    projection_kernel<<<5000, 256, 0, stream>>>(init, cemb, x0, flag);

    countP_kernel<<<384, 256, 0, stream>>>(ei[0], ei[1], ei[2], P);
    cnt_sum_kernel<<<(3 * N + 255) / 256, 256, 0, stream>>>(P, cnt);
    scan_kernel<<<3, 1024, 0, stream>>>(cnt, colp);
    base_kernel<<<(3 * N + 255) / 256, 256, 0, stream>>>(P, colp);
    fill_kernel<<<384, 256, 0, stream>>>(ei[0], ei[1], ei[2], ea[0], ea[1], ea[2],
                                         P, epack, flag);
    degsum_kernel<<<15000, 256, 0, stream>>>(colp, epack, dinv, nloop);
    snorm_sort_kernel<<<15000, 256, 0, stream>>>(colp, epack, dinv);

    const bf16 *i0 = x0, *i1 = x0, *i2 = x0;
    bf16* dsts[3] = {bufA, bufB, bufA};
    for (int l = 0; l < 3; l++) {
        aggregate_kernel<<<15000, 256, 0, stream>>>(i0, i1, i2, ybuf, colp, epack, nloop);
        bf16* dst = dsts[l];
        gemm_relu_kernel<<<1875, 256, 0, stream>>>(ybuf, WT, l, bb[0], bb[1], bb[2],
                                                   dst, dst + SEGEL, dst + 2 * SEGEL, flag);
        i0 = dst; i1 = dst + SEGEL; i2 = dst + 2 * SEGEL;
    }
    attention_kernel<<<5000, 256, 0, stream>>>(bufA, bufA + SEGEL, bufA + 2 * SEGEL,
                                               w_att, d_out, N, flag);
}

// Round 12
// 897.677 us; speedup vs baseline: 1.0075x; 1.0075x over previous
//
#include <hip/hip_runtime.h>
#include <hip/hip_bf16.h>

typedef __hip_bfloat16 bf16;
typedef __bf16 v8bf __attribute__((ext_vector_type(8)));
typedef float f32x4 __attribute__((ext_vector_type(4)));
typedef unsigned int v4u __attribute__((ext_vector_type(4)));

constexpr int N = 20000, M = 1024, E = 640000, D = 256;
constexpr size_t SEGEL = (size_t)N * D;
constexpr int NCHUNK = 10000;
constexpr int NSLICE = 64;
constexpr int ESLICE = E / NSLICE;  // 10000

__device__ __forceinline__ float b2f(bf16 v) { return __bfloat162float(v); }
__device__ __forceinline__ bf16 f2b(float f) { return __float2bfloat16(f); }
__device__ __forceinline__ float u2f(unsigned short u) { return __uint_as_float(((unsigned)u) << 16); }
__device__ __forceinline__ unsigned short f2u(float f) { bf16 h = __float2bfloat16(f); return *(unsigned short*)&h; }
__device__ __forceinline__ float loadf(const void* p, size_t i, int isbf) {
    return isbf ? b2f(((const bf16*)p)[i]) : ((const float*)p)[i];
}
__device__ __forceinline__ void fma8(float* acc, uint4 v, float w) {
    acc[0] = fmaf(w, u2f((unsigned short)(v.x & 0xffffu)), acc[0]);
    acc[1] = fmaf(w, u2f((unsigned short)(v.x >> 16)), acc[1]);
    acc[2] = fmaf(w, u2f((unsigned short)(v.y & 0xffffu)), acc[2]);
    acc[3] = fmaf(w, u2f((unsigned short)(v.y >> 16)), acc[3]);
    acc[4] = fmaf(w, u2f((unsigned short)(v.z & 0xffffu)), acc[4]);
    acc[5] = fmaf(w, u2f((unsigned short)(v.z >> 16)), acc[5]);
    acc[6] = fmaf(w, u2f((unsigned short)(v.w & 0xffffu)), acc[6]);
    acc[7] = fmaf(w, u2f((unsigned short)(v.w >> 16)), acc[7]);
}
__device__ __forceinline__ void add4(float* acc, uint2 v) {
    acc[0] += u2f((unsigned short)(v.x & 0xffffu));
    acc[1] += u2f((unsigned short)(v.x >> 16));
    acc[2] += u2f((unsigned short)(v.y & 0xffffu));
    acc[3] += u2f((unsigned short)(v.y >> 16));
}
__device__ __forceinline__ unsigned pack2(float a, float b) {
    return (unsigned)f2u(a) | ((unsigned)f2u(b) << 16);
}

// ---------------------------------------------------------------------------
__global__ void detect_kernel(const void* __restrict__ ea, int* __restrict__ flag)
{
    if (threadIdx.x == 0 && blockIdx.x == 0) {
        const unsigned short* u = (const unsigned short*)ea;
        int cnt = 0;
        for (int i = 0; i < 64; i++) {
            float f = __uint_as_float(((unsigned)u[i]) << 16);
            if (f >= 0.05f && f <= 1.05f) cnt++;
        }
        *flag = (cnt >= 60) ? 1 : 0;
    }
}

// ---------------------------------------------------------------------------
// Merged weight-transpose (blocks 0..2303) + col-emb MLP table (2304..3327).
__global__ __launch_bounds__(256) void prep_kernel(
    const void* __restrict__ W0, const void* __restrict__ W1, const void* __restrict__ W2,
    const void* __restrict__ pW1, const void* __restrict__ pb1,
    const void* __restrict__ pW2, const void* __restrict__ pb2,
    bf16* __restrict__ WT, bf16* __restrict__ cemb, const int* __restrict__ flag)
{
    int isbf = *flag;
    int b = blockIdx.x;
    if (b < 2304) {
        int mat = b >> 8, n = b & 255, k = threadIdx.x;
        const void* W = (mat < 3) ? W0 : (mat < 6) ? W1 : W2;
        int lm = mat - (mat < 3 ? 0 : (mat < 6 ? 3 : 6));
        WT[(size_t)mat * 65536 + n * 256 + k] =
            f2b(loadf(W, (size_t)lm * 65536 + k * 256 + n, isbf));
    } else {
        int j = b - 2304;           // 0..1023
        int d = threadIdx.x;
        float jf = (float)j;
        float acc = loadf(pb2, d, isbf);
        #pragma unroll
        for (int k = 0; k < 16; k++) {
            float h = fmaxf(jf * loadf(pW1, k, isbf) + loadf(pb1, k, isbf), 0.0f);
            acc += h * loadf(pW2, k * 256 + d, isbf);
        }
        cemb[(size_t)j * 256 + d] = f2b(acc);
    }
}

// ---------------------------------------------------------------------------
// x0[i] = mean_{j: init[i][j]!=0} cemb[j]  — wave per node, sparse gather.
__global__ __launch_bounds__(256) void projection_kernel(
    const void* __restrict__ init, const bf16* __restrict__ cemb,
    bf16* __restrict__ x0, const int* __restrict__ flag)
{
    __shared__ unsigned short idxs[4][1024];
    int isbf = *flag;
    int wave = threadIdx.x >> 6, lane = threadIdx.x & 63;
    int i = blockIdx.x * 4 + wave;
    unsigned long long below = (lane == 63) ? 0x7fffffffffffffffull
                                            : ((1ull << lane) - 1ull);
    int cnt = 0;
    if (isbf) {
        const unsigned short* row = (const unsigned short*)init + (size_t)i * 1024;
        for (int c0 = 0; c0 < 1024; c0 += 64) {
            bool nz = (row[c0 + lane] & 0x7fffu) != 0;
            unsigned long long m = __ballot(nz);
            if (nz) idxs[wave][cnt + __popcll(m & below)] = (unsigned short)(c0 + lane);
            cnt += __popcll(m);
        }
    } else {
        const float* row = (const float*)init + (size_t)i * 1024;
        for (int c0 = 0; c0 < 1024; c0 += 64) {
            bool nz = row[c0 + lane] != 0.0f;
            unsigned long long m = __ballot(nz);
            if (nz) idxs[wave][cnt + __popcll(m & below)] = (unsigned short)(c0 + lane);
            cnt += __popcll(m);
        }
    }
    const uint2* cr = (const uint2*)cemb;     // 64 uint2 per 256-elem row
    float acc[4] = {0.0f, 0.0f, 0.0f, 0.0f};
    int j = 0;
    for (; j + 8 <= cnt; j += 8) {
        uint2 v0 = cr[(size_t)idxs[wave][j + 0] * 64 + lane];
        uint2 v1 = cr[(size_t)idxs[wave][j + 1] * 64 + lane];
        uint2 v2 = cr[(size_t)idxs[wave][j + 2] * 64 + lane];
        uint2 v3 = cr[(size_t)idxs[wave][j + 3] * 64 + lane];
        uint2 v4 = cr[(size_t)idxs[wave][j + 4] * 64 + lane];
        uint2 v5 = cr[(size_t)idxs[wave][j + 5] * 64 + lane];
        uint2 v6 = cr[(size_t)idxs[wave][j + 6] * 64 + lane];
        uint2 v7 = cr[(size_t)idxs[wave][j + 7] * 64 + lane];
        add4(acc, v0); add4(acc, v1); add4(acc, v2); add4(acc, v3);
        add4(acc, v4); add4(acc, v5); add4(acc, v6); add4(acc, v7);
    }
    for (; j < cnt; j++) {
        uint2 v = cr[(size_t)idxs[wave][j] * 64 + lane];
        add4(acc, v);
    }
    float rinv = 1.0f / fmaxf((float)cnt, 1.0f);
    uint2 o;
    o.x = pack2(acc[0] * rinv, acc[1] * rinv);
    o.y = pack2(acc[2] * rinv, acc[3] * rinv);
    ((uint2*)x0)[(size_t)i * 64 + lane] = o;
}

// ---------------------------------------------------------------------------
// Atomic-free CSR build (LDS histogram counting sort), edges packed as int2.
__global__ __launch_bounds__(256) void countP_kernel(
    const int* __restrict__ e0, const int* __restrict__ e1, const int* __restrict__ e2,
    int* __restrict__ P)
{
    __shared__ int cur[NCHUNK];
    int b = blockIdx.x;
    int pb = b >> 7, rem = b & 127;
    int ck = rem >> 6, s = rem & 63;
    const int* ei = pb == 0 ? e0 : pb == 1 ? e1 : e2;
    int c0 = ck * NCHUNK;
    int t = threadIdx.x;
    for (int i = t; i < NCHUNK; i += 256) cur[i] = 0;
    __syncthreads();
    int ebase = s * ESLICE;
    for (int e = ebase + t; e < ebase + ESLICE; e += 256) {
        int c = ei[E + e];
        if (c >= c0 && c < c0 + NCHUNK) atomicAdd(&cur[c - c0], 1);
    }
    __syncthreads();
    int* Prow = P + ((size_t)(pb * NSLICE + s)) * N + c0;
    for (int i = t; i < NCHUNK; i += 256) Prow[i] = cur[i];
}

__global__ __launch_bounds__(256) void cnt_sum_kernel(
    const int* __restrict__ P, int* __restrict__ cnt)
{
    int id = blockIdx.x * 256 + threadIdx.x;
    if (id >= 3 * N) return;
    int pb = id / N, c = id - pb * N;
    int sum = 0;
    #pragma unroll 8
    for (int s = 0; s < NSLICE; s++)
        sum += P[((size_t)(pb * NSLICE + s)) * N + c];
    cnt[id] = sum;
}

__global__ __launch_bounds__(1024) void scan_kernel(
    const int* __restrict__ cnt, int* __restrict__ col_ptr)
{
    int pb = blockIdx.x;
    int base = pb * E;
    __shared__ int s[1024];
    int t = threadIdx.x;
    const int CH = 20;
    int i0 = t * CH;
    int sum = 0;
    for (int j = 0; j < CH; j++) { int i = i0 + j; if (i < N) sum += cnt[pb * N + i]; }
    s[t] = sum;
    __syncthreads();
    for (int off = 1; off < 1024; off <<= 1) {
        int v = (t >= off) ? s[t - off] : 0;
        __syncthreads();
        s[t] += v;
        __syncthreads();
    }
    int run = base + s[t] - sum;
    for (int j = 0; j < CH; j++) {
        int i = i0 + j;
        if (i < N) {
            col_ptr[pb * (N + 1) + i] = run;
            run += cnt[pb * N + i];
        }
    }
    if (t == 0) col_ptr[pb * (N + 1) + N] = base + E;
}

__global__ __launch_bounds__(256) void base_kernel(
    int* __restrict__ P, const int* __restrict__ col_ptr)
{
    int id = blockIdx.x * 256 + threadIdx.x;
    if (id >= 3 * N) return;
    int pb = id / N, c = id - pb * N;
    int run = col_ptr[pb * (N + 1) + c];
    for (int s = 0; s < NSLICE; s++) {
        size_t idx = ((size_t)(pb * NSLICE + s)) * N + c;
        int v = P[idx];
        P[idx] = run;
        run += v;
    }
}

// epack[pos] = (row, raw weight bits)
__global__ __launch_bounds__(256) void fill_kernel(
    const int* __restrict__ e0, const int* __restrict__ e1, const int* __restrict__ e2,
    const void* __restrict__ a0, const void* __restrict__ a1, const void* __restrict__ a2,
    const int* __restrict__ P, int2* __restrict__ epack, const int* __restrict__ flag)
{
    __shared__ int cur[NCHUNK];
    int isbf = *flag;
    int b = blockIdx.x;
    int pb = b >> 7, rem = b & 127;
    int ck = rem >> 6, s = rem & 63;
    const int* ei = pb == 0 ? e0 : pb == 1 ? e1 : e2;
    const void* ea = pb == 0 ? a0 : pb == 1 ? a1 : a2;
    int c0 = ck * NCHUNK;
    int t = threadIdx.x;
    const int* Prow = P + ((size_t)(pb * NSLICE + s)) * N + c0;
    for (int i = t; i < NCHUNK; i += 256) cur[i] = Prow[i];
    __syncthreads();
    int ebase = s * ESLICE;
    for (int e = ebase + t; e < ebase + ESLICE; e += 256) {
        int c = ei[E + e];
        if (c >= c0 && c < c0 + NCHUNK) {
            int r = ei[e];
            float w = loadf(ea, e, isbf);
            int pos = atomicAdd(&cur[c - c0], 1);
            int2 v; v.x = r; v.y = __float_as_int(w);
            epack[pos] = v;
        }
    }
}

// deg = 1 + sum(w_raw) -> dinv, nloop  (wave per node)
__global__ __launch_bounds__(256) void degsum_kernel(
    const int* __restrict__ col_ptr, const int2* __restrict__ epack,
    float* __restrict__ dinv, float* __restrict__ nloop)
{
    int wave = threadIdx.x >> 6, lane = threadIdx.x & 63;
    int pb = blockIdx.x / 5000;
    int i = (blockIdx.x - pb * 5000) * 4 + wave;
    int start = col_ptr[pb * (N + 1) + i], end = col_ptr[pb * (N + 1) + i + 1];
    float sum = 0.0f;
    for (int p = start + lane; p < end; p += 64) sum += __int_as_float(epack[p].y);
    for (int off = 1; off < 64; off <<= 1) sum += __shfl_xor(sum, off, 64);
    if (lane == 0) {
        float dg = 1.0f + sum;
        dinv[pb * N + i] = rsqrtf(dg);
        nloop[pb * N + i] = 1.0f / dg;
    }
}

// epack[p].y = dinv[c]*w_raw*dinv[r], then per-64-chunk bitonic sort by src
// (sorted lists -> concurrent waves share a moving L2 window).
__global__ __launch_bounds__(256) void snorm_sort_kernel(
    const int* __restrict__ col_ptr, int2* __restrict__ epack,
    const float* __restrict__ dinv)
{
    int wave = threadIdx.x >> 6, lane = threadIdx.x & 63;
    int pb = blockIdx.x / 5000;
    int i = (blockIdx.x - pb * 5000) * 4 + wave;
    int start = col_ptr[pb * (N + 1) + i], end = col_ptr[pb * (N + 1) + i + 1];
    float dc = dinv[pb * N + i];
    for (int base = start; base < end; base += 64) {
        int n = end - base; n = n < 64 ? n : 64;
        int key = 0x7fffffff, val = 0;
        if (lane < n) {
            int2 v = epack[base + lane];
            key = v.x;
            val = __float_as_int(dc * __int_as_float(v.y) * dinv[pb * N + v.x]);
        }
        #pragma unroll
        for (int k = 2; k <= 64; k <<= 1) {
            #pragma unroll
            for (int j = k >> 1; j > 0; j >>= 1) {
                int pk = __shfl_xor(key, j, 64);
                int pv = __shfl_xor(val, j, 64);
                bool up = (lane & k) == 0;
                bool lower = (lane & j) == 0;
                bool takeMin = (up == lower);
                bool sw = takeMin ? (pk < key) : (pk > key);
                if (sw) { key = pk; val = pv; }
            }
        }
        if (lane < n) {
            int2 o; o.x = key; o.y = val;
            epack[base + lane] = o;
        }
    }
}

// ---------------------------------------------------------------------------
// Wave-per-node aggregation; half-wave per edge, 16B gathers; explicit 8-deep
// software pipeline (named-register buffers, uniform guards) to force 8
// outstanding LLC gathers per wave (R10 asm held only ~2-3: VGPR_Count=20).
__global__ __launch_bounds__(256) void aggregate_kernel(
    const bf16* __restrict__ xi0, const bf16* __restrict__ xi1, const bf16* __restrict__ xi2,
    bf16* __restrict__ yb,
    const int* __restrict__ col_ptr, const int2* __restrict__ epack,
    const float* __restrict__ nloop)
{
    int wave = threadIdx.x >> 6, lane = threadIdx.x & 63;
    int pb = blockIdx.x / 5000;
    int i = (blockIdx.x - pb * 5000) * 4 + wave;
    const bf16* x = pb == 0 ? xi0 : pb == 1 ? xi1 : xi2;
    const uint4* xr = (const uint4*)x;           // 32 uint4 per row
    int L = lane & 31, h = lane >> 5;
    int start = col_ptr[pb * (N + 1) + i], end = col_ptr[pb * (N + 1) + i + 1];
    float nl = nloop[pb * N + i];
    float acc[8];
    {
        uint4 sv = xr[(size_t)i * 32 + L];
        float self = (h == 0) ? nl : 0.0f;
        #pragma unroll
        for (int j = 0; j < 8; j++) acc[j] = 0.0f;
        fma8(acc, sv, self);
    }
    for (int base = start; base < end; base += 64) {
        int n = end - base; n = n < 64 ? n : 64;
        int ex = 0, ey = 0;
        if (lane < n) {
            unsigned long long ev = __builtin_nontemporal_load(
                (const unsigned long long*)(epack + base + lane));
            ex = (int)(unsigned)(ev & 0xffffffffull);
            ey = (int)(unsigned)(ev >> 32);
        }
        int pmax = (n + 1) >> 1;                 // wave-uniform pair count
        for (int p0 = 0; p0 < pmax; p0 += 8) {
            int m = pmax - p0; m = m < 8 ? m : 8;   // wave-uniform
            uint4 v[8];
            float w[8];
            #pragma unroll
            for (int k = 0; k < 8; k++) {
                int e = 2 * (p0 + k) + h;        // <= 63 always: shfl-safe
                int rj = __shfl(ex, e, 64);      // lanes >= n hold ex=0 -> row 0 (cached)
                w[k] = __int_as_float(__shfl(ey, e, 64));  // ey=0 for invalid -> w=0
                if (k < m) v[k] = xr[(size_t)rj * 32 + L];
            }
            #pragma unroll
            for (int k = 0; k < 8; k++)
                if (k < m) fma8(acc, v[k], w[k]);
        }
    }
    #pragma unroll
    for (int j = 0; j < 8; j++) acc[j] += __shfl_xor(acc[j], 32, 64);
    if (h == 0) {
        v4u o;
        o.x = pack2(acc[0], acc[1]);
        o.y = pack2(acc[2], acc[3]);
        o.z = pack2(acc[4], acc[5]);
        o.w = pack2(acc[6], acc[7]);
        __builtin_nontemporal_store(o,
            (v4u*)yb + (size_t)pb * (SEGEL / 8) + (size_t)i * 32 + L);
    }
}

// ---------------------------------------------------------------------------
// xout = relu(y @ W + b). One block per 32 rows x full 256 cols (y read once).
__global__ __launch_bounds__(256) void gemm_relu_kernel(
    const bf16* __restrict__ yb, const bf16* __restrict__ WT, int layer,
    const void* __restrict__ b0, const void* __restrict__ b1, const void* __restrict__ b2,
    bf16* __restrict__ o0, bf16* __restrict__ o1, bf16* __restrict__ o2,
    const int* __restrict__ flag)
{
    int isbf = *flag;
    int pl = blockIdx.x / 625, blk = blockIdx.x - pl * 625;
    const bf16* y = yb + (size_t)pl * SEGEL;
    const bf16* wt = WT + (size_t)(pl * 3 + layer) * 65536;
    const void* bias = pl == 0 ? b0 : pl == 1 ? b1 : b2;
    bf16* xout = pl == 0 ? o0 : pl == 1 ? o1 : o2;

    int wave = threadIdx.x >> 6, lane = threadIdx.x & 63;
    int m0 = blk * 32 + (wave >> 1) * 16;
    int n0 = (wave & 1) * 128;
    int mrow = lane & 15, q = lane >> 4;

    f32x4 acc[8] = {};
    const v8bf* arow = reinterpret_cast<const v8bf*>(y + (size_t)(m0 + mrow) * 256);
    for (int k0 = 0; k0 < 256; k0 += 32) {
        v8bf a = arow[(k0 >> 3) + q];
        #pragma unroll
        for (int nt = 0; nt < 8; nt++) {
            const v8bf* brow = reinterpret_cast<const v8bf*>(wt + (size_t)(n0 + nt * 16 + mrow) * 256);
            acc[nt] = __builtin_amdgcn_mfma_f32_16x16x32_bf16(a, brow[(k0 >> 3) + q], acc[nt], 0, 0, 0);
        }
    }
    #pragma unroll
    for (int nt = 0; nt < 8; nt++) {
        int col = n0 + nt * 16 + mrow;
        float bv = loadf(bias, (size_t)layer * 256 + col, isbf);
        #pragma unroll
        for (int r = 0; r < 4; r++) {
            int row = m0 + q * 4 + r;
            xout[(size_t)row * 256 + col] = f2b(fmaxf(acc[nt][r] + bv, 0.0f));
        }
    }
}

// ---------------------------------------------------------------------------
__global__ __launch_bounds__(256) void attention_kernel(
    const bf16* __restrict__ e0, const bf16* __restrict__ e1, const bf16* __restrict__ e2,
    const void* __restrict__ w_att, void* __restrict__ out, int n_nodes,
    const int* __restrict__ flag)
{
    int isbf = *flag;
    int wave = threadIdx.x >> 6, lane = threadIdx.x & 63;
    int n = blockIdx.x * 4 + wave;
    if (n >= n_nodes) return;
    int d0 = lane * 4;
    float w[4], v0[4], v1[4], v2[4];
    #pragma unroll
    for (int j = 0; j < 4; j++) {
        w[j]  = loadf(w_att, d0 + j, isbf);
        v0[j] = b2f(e0[(size_t)n * 256 + d0 + j]);
        v1[j] = b2f(e1[(size_t)n * 256 + d0 + j]);
        v2[j] = b2f(e2[(size_t)n * 256 + d0 + j]);
    }
    float s0 = 0, s1 = 0, s2 = 0;
    #pragma unroll
    for (int j = 0; j < 4; j++) { s0 += v0[j] * w[j]; s1 += v1[j] * w[j]; s2 += v2[j] * w[j]; }
    for (int off = 1; off < 64; off <<= 1) {
        s0 += __shfl_xor(s0, off, 64);
        s1 += __shfl_xor(s1, off, 64);
        s2 += __shfl_xor(s2, off, 64);
    }
    float m = fmaxf(s0, fmaxf(s1, s2));
    float a0 = expf(s0 - m), a1 = expf(s1 - m), a2 = expf(s2 - m);
    float inv = 1.0f / (a0 + a1 + a2);
    a0 *= inv; a1 *= inv; a2 *= inv;
    #pragma unroll
    for (int j = 0; j < 4; j++) {
        float v = a0 * v0[j] + a1 * v1[j] + a2 * v2[j];
        if (isbf) ((bf16*)out)[(size_t)n * 256 + d0 + j] = f2b(v);
        else      ((float*)out)[(size_t)n * 256 + d0 + j] = v;
    }
}

// ---------------------------------------------------------------------------
extern "C" void kernel_launch(void* const* d_in, const int* in_sizes, int n_in,
                              void* d_out, int out_size, void* d_ws, size_t ws_size,
                              hipStream_t stream)
{
    (void)in_sizes; (void)n_in; (void)out_size; (void)ws_size;

    const void* init = d_in[0];
    const int*  ei[3] = {(const int*)d_in[1], (const int*)d_in[2], (const int*)d_in[3]};
    const void* ea[3] = {d_in[4], d_in[5], d_in[6]};
    const void* pW1 = d_in[7];
    const void* pb1 = d_in[8];
    const void* pW2 = d_in[9];
    const void* pb2 = d_in[10];
    const void* Wb[3] = {d_in[11], d_in[13], d_in[15]};
    const void* bb[3] = {d_in[12], d_in[14], d_in[16]};
    const void* w_att = d_in[17];

    char* ws = (char*)d_ws;
    size_t off = 0;
    auto carve = [&](size_t bytes) -> char* {
        off = (off + 255) & ~(size_t)255;
        char* p = ws + off; off += bytes; return p;
    };
    int*   flag  = (int*)carve(4);
    bf16*  WT    = (bf16*)carve((size_t)9 * 65536 * 2);
    bf16*  cemb  = (bf16*)carve((size_t)M * D * 2);
    bf16*  x0    = (bf16*)carve(SEGEL * 2);
    int*   cnt   = (int*)carve((size_t)3 * N * 4);
    int*   colp  = (int*)carve((size_t)3 * (N + 1) * 4);
    float* dinv  = (float*)carve((size_t)3 * N * 4);
    float* nloop = (float*)carve((size_t)3 * N * 4);
    int2*  epack = (int2*)carve((size_t)3 * E * 8);
    bf16*  ybuf  = (bf16*)carve((size_t)3 * SEGEL * 2);
    bf16*  bufA  = (bf16*)carve((size_t)3 * SEGEL * 2);
    bf16*  bufB  = (bf16*)carve((size_t)3 * SEGEL * 2);
    // P (15.36 MB) aliases bufB: dead before bufB's first write (layer-1 out)
    int* P = (int*)bufB;

    detect_kernel<<<1, 64, 0, stream>>>(ea[0], flag);
    prep_kernel<<<3328, 256, 0, stream>>>(Wb[0], Wb[1], Wb[2],
                                          pW1, pb1, pW2, pb2, WT, cemb, flag);
    projection_kernel<<<5000, 256, 0, stream>>>(init, cemb, x0, flag);

    countP_kernel<<<384, 256, 0, stream>>>(ei[0], ei[1], ei[2], P);
    cnt_sum_kernel<<<(3 * N + 255) / 256, 256, 0, stream>>>(P, cnt);
    scan_kernel<<<3, 1024, 0, stream>>>(cnt, colp);
    base_kernel<<<(3 * N + 255) / 256, 256, 0, stream>>>(P, colp);
    fill_kernel<<<384, 256, 0, stream>>>(ei[0], ei[1], ei[2], ea[0], ea[1], ea[2],
                                         P, epack, flag);
    degsum_kernel<<<15000, 256, 0, stream>>>(colp, epack, dinv, nloop);
    snorm_sort_kernel<<<15000, 256, 0, stream>>>(colp, epack, dinv);

    const bf16 *i0 = x0, *i1 = x0, *i2 = x0;
    bf16* dsts[3] = {bufA, bufB, bufA};
    for (int l = 0; l < 3; l++) {
        aggregate_kernel<<<15000, 256, 0, stream>>>(i0, i1, i2, ybuf, colp, epack, nloop);
        bf16* dst = dsts[l];
        gemm_relu_kernel<<<1875, 256, 0, stream>>>(ybuf, WT, l, bb[0], bb[1], bb[2],
                                                   dst, dst + SEGEL, dst + 2 * SEGEL, flag);
        i0 = dst; i1 = dst + SEGEL; i2 = dst + 2 * SEGEL;
    }
    attention_kernel<<<5000, 256, 0, stream>>>(bufA, bufA + SEGEL, bufA + 2 * SEGEL,
                                               w_att, d_out, N, flag);
}